// Round 5
// baseline (1221.422 us; speedup 1.0000x reference)
//
#include <hip/hip_runtime.h>

// SSIM loss, round-14: zero-LDS register design, OCCUPANCY FIXED.
//
// Round-4 post-mortem: spill eliminated (WRITE_SIZE 1.32 GB -> 120 B,
// VGPR 84 -> 236) — but 236 VGPR lands in the 2-waves/SIMD band and
// measured occupancy was 0.9 waves/SIMD: the per-wave stall chain
// (vmcnt + 20 dependent bpermutes/row) has no co-resident wave to hide
// under. VALUBusy 31%, dur 243 us vs ~38 us issue floor. True working
// set is ~110 regs; the allocator used 236 only because (64,1) gave it
// an unlimited budget. Fix:
//  1. __attribute__((amdgpu_waves_per_eu(4))): allocator budget 512/4
//     = 128 VGPR -> 4 waves/SIMD (the documented backend knob, not the
//     launch_bounds 2nd-arg semantics that mis-capped round 3).
//  2. Gaussian symmetry w[k]==w[10-k]: 6 weight regs instead of 11.
// Everything else byte-identical to the passing round-13 kernel.
// Predicted: VGPR <=128, WRITE_SIZE stays ~0.1 MB (spill detector),
// Occupancy 11 -> 30-45%, VALUBusy 31 -> 60-80%, dur 243 -> 60-100 us.

#define WSZ    11
#define RAD    5
#define IMGN   48
#define IMGH   512
#define IMGW   512
#define OUTC   54               // valid output cols per 64-lane band
#define NBAND  10               // ceil(512/54)
#define NSTRIP 8
#define STRIPR 64               // output rows per strip
#define NBLK   (IMGN * NBAND * NSTRIP)   // 3840

// Symmetric Gaussian taps: w[k] == w[10-k], 6 unique values. Index folds
// to a constant after unrolling (k is always a compile-time constant).
#define W(k) wv[(k) < 6 ? (k) : 10 - (k)]

// Issue prefetch of input row (ir) into named pf slot PFS. Row clamped
// (always a legal address); OOB rows are zeroed at consume via fm_.
#define ISSUE(PFS, ir)                                                  \
    {                                                                   \
        const int rc_ = min(max((ir), 0), IMGH - 1);                    \
        pfp_##PFS = p[rc_ * IMGW + colc];                               \
        pft_##PFS = q[rc_ * IMGW + colc];                               \
    }

// Consume pf slot PFS (input row ir), immediately reissue row ir+4 into
// the same slot, h-blur via bpermute, deposit into named ring slot SLOT.
// Tap k reads lane (t-5+k): address = bpbase + 4k, 4k in [0,40] folds
// into the DS offset immediate. Wrap garbage reaches only masked lanes.
#define HROW(SLOT, PFS, ir)                                             \
    {                                                                   \
        const float rawp_ = pfp_##PFS, rawt_ = pft_##PFS;               \
        ISSUE(PFS, (ir) + 4)                                            \
        const float fm_ =                                               \
            ((unsigned)(ir) < (unsigned)IMGH) ? loadm : 0.f;            \
        const float pv_ = rawp_ * fm_;                                  \
        const float tv_ = rawt_ * fm_;                                  \
        const int pb_ = __float_as_int(pv_);                            \
        const int tb_ = __float_as_int(tv_);                            \
        float f0_ = W(RAD) * pv_;                                       \
        float f1_ = W(RAD) * tv_;                                       \
        float f2_ = W(RAD) * (pv_ * pv_ + tv_ * tv_);                   \
        float f3_ = W(RAD) * (pv_ * tv_);                               \
        _Pragma("unroll")                                               \
        for (int k = 0; k < WSZ; ++k) {                                 \
            if (k == RAD) continue;                                     \
            const float sp_ = __int_as_float(                           \
                __builtin_amdgcn_ds_bpermute(bpbase + (k << 2), pb_));  \
            const float st_ = __int_as_float(                           \
                __builtin_amdgcn_ds_bpermute(bpbase + (k << 2), tb_));  \
            f0_ += W(k) * sp_;                                          \
            f1_ += W(k) * st_;                                          \
            f2_ += W(k) * (sp_ * sp_ + st_ * st_);                      \
            f3_ += W(k) * (sp_ * st_);                                  \
        }                                                               \
        g0_##SLOT = f0_; g1_##SLOT = f1_;                               \
        g2_##SLOT = f2_; g3_##SLOT = f3_;                               \
    }

// Vertical 11-tap over 11 NAMED ring slots (S0..S10 = rows m-5..m+5,
// weights W(0)..W(10)) + SSIM accumulate.
#define VOUT(S0,S1,S2,S3,S4,S5,S6,S7,S8,S9,S10)                         \
    {                                                                   \
        const float a0_ =                                               \
            W(0)*g0_##S0 + W(1)*g0_##S1 + W(2)*g0_##S2 + W(3)*g0_##S3   \
          + W(4)*g0_##S4 + W(5)*g0_##S5 + W(6)*g0_##S6 + W(7)*g0_##S7   \
          + W(8)*g0_##S8 + W(9)*g0_##S9 + W(10)*g0_##S10;               \
        const float a1_ =                                               \
            W(0)*g1_##S0 + W(1)*g1_##S1 + W(2)*g1_##S2 + W(3)*g1_##S3   \
          + W(4)*g1_##S4 + W(5)*g1_##S5 + W(6)*g1_##S6 + W(7)*g1_##S7   \
          + W(8)*g1_##S8 + W(9)*g1_##S9 + W(10)*g1_##S10;               \
        const float a2_ =                                               \
            W(0)*g2_##S0 + W(1)*g2_##S1 + W(2)*g2_##S2 + W(3)*g2_##S3   \
          + W(4)*g2_##S4 + W(5)*g2_##S5 + W(6)*g2_##S6 + W(7)*g2_##S7   \
          + W(8)*g2_##S8 + W(9)*g2_##S9 + W(10)*g2_##S10;               \
        const float a3_ =                                               \
            W(0)*g3_##S0 + W(1)*g3_##S1 + W(2)*g3_##S2 + W(3)*g3_##S3   \
          + W(4)*g3_##S4 + W(5)*g3_##S5 + W(6)*g3_##S6 + W(7)*g3_##S7   \
          + W(8)*g3_##S8 + W(9)*g3_##S9 + W(10)*g3_##S10;               \
        const float m1_ = a0_, m2_ = a1_;                               \
        const float m1sq_ = m1_ * m1_, m2sq_ = m2_ * m2_;               \
        const float m12_ = m1_ * m2_;                                   \
        const float vs_ = a2_ - m1sq_ - m2sq_;                          \
        const float cv_ = a3_ - m12_;                                   \
        const float num_ = (2.f * m12_ + 1e-4f) * (2.f * cv_ + 9e-4f);  \
        const float den_ =                                              \
            (m1sq_ + m2sq_ + 1e-4f) * (vs_ + 9e-4f) + 1e-8f;            \
        local += outm * (num_ / den_);                                  \
    }

__global__ void __launch_bounds__(64)
__attribute__((amdgpu_waves_per_eu(4))) ssim_vreg_kernel(
    const float* __restrict__ pred,
    const float* __restrict__ target,
    const float* __restrict__ window,
    double* __restrict__ slots)        // NBLK slots, plain write per block
{
    const int t = threadIdx.x;

    // Separable 1D window from row sums; symmetric -> 6 unique taps,
    // broadcast via shuffles.
    float rsum = 0.f;
    if (t < WSZ) {
        #pragma unroll
        for (int j = 0; j < WSZ; ++j) rsum += window[t * WSZ + j];
    }
    float wv[6];
    #pragma unroll
    for (int k = 0; k < 6; ++k) wv[k] = __shfl(rsum, k, 64);

    // Block decode: 48 img x 10 bands x 8 strips.
    const int strip = blockIdx.x & (NSTRIP - 1);
    const int rem   = blockIdx.x >> 3;
    const int band  = rem % NBAND;
    const int img   = rem / NBAND;

    // Lane t covers input column band*54 + t - 5 (clamped + masked).
    const int col  = band * OUTC + t - RAD;
    const int colc = min(max(col, 0), IMGW - 1);
    const float loadm = (col >= 0 && col < IMGW) ? 1.f : 0.f;
    // Valid output lanes: 5..58 (full h-neighborhood) and col < 512.
    const float outm =
        (t >= RAD && t < RAD + OUTC && col < IMGW) ? 1.f : 0.f;

    const int base = strip * STRIPR;   // first output row; base % 16 == 0

    const float* __restrict__ p = pred   + (size_t)img * (IMGH * IMGW);
    const float* __restrict__ q = target + (size_t)img * (IMGH * IMGW);

    // Single bpermute base: tap k of lane t pulls lane (t-5+k), i.e.
    // byte addr ((t-5)<<2) + (k<<2); k<<2 folds into the DS immediate.
    const int bpbase = (t - RAD) << 2;

    // NAMED register ring: slot i holds row r (r mod 16 == i), 4 fields.
    float g0_0=0,g0_1=0,g0_2=0,g0_3=0,g0_4=0,g0_5=0,g0_6=0,g0_7=0,
          g0_8=0,g0_9=0,g0_10=0,g0_11=0,g0_12=0,g0_13=0,g0_14=0,g0_15=0;
    float g1_0=0,g1_1=0,g1_2=0,g1_3=0,g1_4=0,g1_5=0,g1_6=0,g1_7=0,
          g1_8=0,g1_9=0,g1_10=0,g1_11=0,g1_12=0,g1_13=0,g1_14=0,g1_15=0;
    float g2_0=0,g2_1=0,g2_2=0,g2_3=0,g2_4=0,g2_5=0,g2_6=0,g2_7=0,
          g2_8=0,g2_9=0,g2_10=0,g2_11=0,g2_12=0,g2_13=0,g2_14=0,g2_15=0;
    float g3_0=0,g3_1=0,g3_2=0,g3_3=0,g3_4=0,g3_5=0,g3_6=0,g3_7=0,
          g3_8=0,g3_9=0,g3_10=0,g3_11=0,g3_12=0,g3_13=0,g3_14=0,g3_15=0;
    // Named prefetch ring, depth 4 (slot = row & 3).
    float pfp_0, pfp_1, pfp_2, pfp_3, pft_0, pft_1, pft_2, pft_3;
    float local = 0.f;

    // Initial prefetch: rows base-5..base-2 into slot row&3 (base%4==0).
    ISSUE(3, base - 5)
    ISSUE(0, base - 4)
    ISSUE(1, base - 3)
    ISSUE(2, base - 2)

    // Prologue: h-blur rows base-5..base+4 into ring slots row&15.
    HROW(11, 3, base - 5)
    HROW(12, 0, base - 4)
    HROW(13, 1, base - 3)
    HROW(14, 2, base - 2)
    HROW(15, 3, base - 1)
    HROW(0,  0, base + 0)
    HROW(1,  1, base + 1)
    HROW(2,  2, base + 2)
    HROW(3,  3, base + 3)
    HROW(4,  0, base + 4)

    // Main: 4 x 16 output rows; every ring/pf reference is a named scalar.
    #pragma unroll 1
    for (int mb = 0; mb < 4; ++mb) {
        const int rb = base + mb * 16;
        HROW(5,  1, rb + 5)   VOUT(11,12,13,14,15,0,1,2,3,4,5)
        HROW(6,  2, rb + 6)   VOUT(12,13,14,15,0,1,2,3,4,5,6)
        HROW(7,  3, rb + 7)   VOUT(13,14,15,0,1,2,3,4,5,6,7)
        HROW(8,  0, rb + 8)   VOUT(14,15,0,1,2,3,4,5,6,7,8)
        HROW(9,  1, rb + 9)   VOUT(15,0,1,2,3,4,5,6,7,8,9)
        HROW(10, 2, rb + 10)  VOUT(0,1,2,3,4,5,6,7,8,9,10)
        HROW(11, 3, rb + 11)  VOUT(1,2,3,4,5,6,7,8,9,10,11)
        HROW(12, 0, rb + 12)  VOUT(2,3,4,5,6,7,8,9,10,11,12)
        HROW(13, 1, rb + 13)  VOUT(3,4,5,6,7,8,9,10,11,12,13)
        HROW(14, 2, rb + 14)  VOUT(4,5,6,7,8,9,10,11,12,13,14)
        HROW(15, 3, rb + 15)  VOUT(5,6,7,8,9,10,11,12,13,14,15)
        HROW(0,  0, rb + 16)  VOUT(6,7,8,9,10,11,12,13,14,15,0)
        HROW(1,  1, rb + 17)  VOUT(7,8,9,10,11,12,13,14,15,0,1)
        HROW(2,  2, rb + 18)  VOUT(8,9,10,11,12,13,14,15,0,1,2)
        HROW(3,  3, rb + 19)  VOUT(9,10,11,12,13,14,15,0,1,2,3)
        HROW(4,  0, rb + 20)  VOUT(10,11,12,13,14,15,0,1,2,3,4)
    }

    // Wave shuffle reduce; lane 0 writes this block's slot (no atomic).
    #pragma unroll
    for (int off = 32; off > 0; off >>= 1)
        local += __shfl_down(local, off, 64);
    if (t == 0) slots[blockIdx.x] = (double)local;
}

__global__ __launch_bounds__(256) void ssim_finalize_kernel(
    const double* __restrict__ slots, float* __restrict__ out, double invN)
{
    __shared__ double red[4];
    const int t = threadIdx.x;
    double s = 0.0;
    for (int i = t; i < NBLK; i += 256) s += slots[i];
    #pragma unroll
    for (int off = 32; off > 0; off >>= 1)
        s += __shfl_down(s, off, 64);
    const int lane = t & 63, wid = t >> 6;
    if (lane == 0) red[wid] = s;
    __syncthreads();
    if (t == 0)
        out[0] = (float)(1.0 - (red[0] + red[1] + red[2] + red[3]) * invN);
}

extern "C" void kernel_launch(void* const* d_in, const int* in_sizes, int n_in,
                              void* d_out, int out_size, void* d_ws, size_t ws_size,
                              hipStream_t stream)
{
    const float* pred   = (const float*)d_in[0];
    const float* target = (const float*)d_in[1];
    const float* window = (const float*)d_in[2];
    float*  out   = (float*)d_out;
    double* slots = (double*)d_ws;     // NBLK*8 = 30.7 KB; every slot
                                       // written each launch (poison ok).

    ssim_vreg_kernel<<<NBLK, 64, 0, stream>>>(pred, target, window, slots);

    const double invN = 1.0 / ((double)IMGN * IMGH * IMGW);
    ssim_finalize_kernel<<<1, 256, 0, stream>>>(slots, out, invN);
}

// Round 6
// 551.781 us; speedup vs baseline: 2.2136x; 2.2136x over previous
//
#include <hip/hip_runtime.h>

// SSIM loss, round-15: zero-LDS register design, BUDGET = 128 VIA (64,2).
//
// Empirical register-budget law from rounds 3/4/5 (three data points):
//   budget ~= 512 / (2 * min_waves_arg)
//   (64,3) -> 84, (64,1) -> 236<=256, waves_per_eu(4) -> 64.
// Round-3 (84) and round-5 (64) sat BELOW the ~110-reg working set ->
// catastrophic scratch spill (WRITE_SIZE 1.3-2.1 GB). Round-4 (256
// budget) fit but ballooned to 236 VGPR -> 2-waves/SIMD band, latency
// bound (VALUBusy 31%, 243 us). Fix: __launch_bounds__(64, 2) -> budget
// 128: above the working set (no spill), inside the 4-waves/SIMD band
// (2x round-4's latency cover). Algorithm unchanged (passing since r12):
//  - h-blur via ds_bpermute (lane=column), zero LDS, zero barriers;
//  - v-blur from 16-slot named-register ring (4 fields);
//  - 4-deep named prefetch ring, reissue-at-consume;
//  - 48 img x 10 bands(54 cols) x 8 strips(64 rows) = 3840 1-wave blocks.
// Predicted: VGPR ~128, WRITE_SIZE stays ~120 B (spill detector),
// VALUBusy 31 -> 55-75%, dur 243 -> 90-130 us.

#define WSZ    11
#define RAD    5
#define IMGN   48
#define IMGH   512
#define IMGW   512
#define OUTC   54               // valid output cols per 64-lane band
#define NBAND  10               // ceil(512/54)
#define NSTRIP 8
#define STRIPR 64               // output rows per strip
#define NBLK   (IMGN * NBAND * NSTRIP)   // 3840

// Symmetric Gaussian taps: w[k] == w[10-k], 6 unique registers. Index
// folds to a constant after unrolling (k always compile-time constant).
#define W(k) wv[(k) < 6 ? (k) : 10 - (k)]

// Issue prefetch of input row (ir) into named pf slot PFS. Row clamped
// (always a legal address); OOB rows are zeroed at consume via fm_.
#define ISSUE(PFS, ir)                                                  \
    {                                                                   \
        const int rc_ = min(max((ir), 0), IMGH - 1);                    \
        pfp_##PFS = p[rc_ * IMGW + colc];                               \
        pft_##PFS = q[rc_ * IMGW + colc];                               \
    }

// Consume pf slot PFS (input row ir), immediately reissue row ir+4 into
// the same slot, h-blur via bpermute, deposit into named ring slot SLOT.
// Tap k reads lane (t-5+k): address = bpbase + 4k; 4k in [0,40] folds
// into the DS offset immediate. Wrap garbage reaches only masked lanes.
#define HROW(SLOT, PFS, ir)                                             \
    {                                                                   \
        const float rawp_ = pfp_##PFS, rawt_ = pft_##PFS;               \
        ISSUE(PFS, (ir) + 4)                                            \
        const float fm_ =                                               \
            ((unsigned)(ir) < (unsigned)IMGH) ? loadm : 0.f;            \
        const float pv_ = rawp_ * fm_;                                  \
        const float tv_ = rawt_ * fm_;                                  \
        const int pb_ = __float_as_int(pv_);                            \
        const int tb_ = __float_as_int(tv_);                            \
        float f0_ = W(RAD) * pv_;                                       \
        float f1_ = W(RAD) * tv_;                                       \
        float f2_ = W(RAD) * (pv_ * pv_ + tv_ * tv_);                   \
        float f3_ = W(RAD) * (pv_ * tv_);                               \
        _Pragma("unroll")                                               \
        for (int k = 0; k < WSZ; ++k) {                                 \
            if (k == RAD) continue;                                     \
            const float sp_ = __int_as_float(                           \
                __builtin_amdgcn_ds_bpermute(bpbase + (k << 2), pb_));  \
            const float st_ = __int_as_float(                           \
                __builtin_amdgcn_ds_bpermute(bpbase + (k << 2), tb_));  \
            f0_ += W(k) * sp_;                                          \
            f1_ += W(k) * st_;                                          \
            f2_ += W(k) * (sp_ * sp_ + st_ * st_);                      \
            f3_ += W(k) * (sp_ * st_);                                  \
        }                                                               \
        g0_##SLOT = f0_; g1_##SLOT = f1_;                               \
        g2_##SLOT = f2_; g3_##SLOT = f3_;                               \
    }

// Vertical 11-tap over 11 NAMED ring slots (S0..S10 = rows m-5..m+5,
// weights W(0)..W(10)) + SSIM accumulate.
#define VOUT(S0,S1,S2,S3,S4,S5,S6,S7,S8,S9,S10)                         \
    {                                                                   \
        const float a0_ =                                               \
            W(0)*g0_##S0 + W(1)*g0_##S1 + W(2)*g0_##S2 + W(3)*g0_##S3   \
          + W(4)*g0_##S4 + W(5)*g0_##S5 + W(6)*g0_##S6 + W(7)*g0_##S7   \
          + W(8)*g0_##S8 + W(9)*g0_##S9 + W(10)*g0_##S10;               \
        const float a1_ =                                               \
            W(0)*g1_##S0 + W(1)*g1_##S1 + W(2)*g1_##S2 + W(3)*g1_##S3   \
          + W(4)*g1_##S4 + W(5)*g1_##S5 + W(6)*g1_##S6 + W(7)*g1_##S7   \
          + W(8)*g1_##S8 + W(9)*g1_##S9 + W(10)*g1_##S10;               \
        const float a2_ =                                               \
            W(0)*g2_##S0 + W(1)*g2_##S1 + W(2)*g2_##S2 + W(3)*g2_##S3   \
          + W(4)*g2_##S4 + W(5)*g2_##S5 + W(6)*g2_##S6 + W(7)*g2_##S7   \
          + W(8)*g2_##S8 + W(9)*g2_##S9 + W(10)*g2_##S10;               \
        const float a3_ =                                               \
            W(0)*g3_##S0 + W(1)*g3_##S1 + W(2)*g3_##S2 + W(3)*g3_##S3   \
          + W(4)*g3_##S4 + W(5)*g3_##S5 + W(6)*g3_##S6 + W(7)*g3_##S7   \
          + W(8)*g3_##S8 + W(9)*g3_##S9 + W(10)*g3_##S10;               \
        const float m1_ = a0_, m2_ = a1_;                               \
        const float m1sq_ = m1_ * m1_, m2sq_ = m2_ * m2_;               \
        const float m12_ = m1_ * m2_;                                   \
        const float vs_ = a2_ - m1sq_ - m2sq_;                          \
        const float cv_ = a3_ - m12_;                                   \
        const float num_ = (2.f * m12_ + 1e-4f) * (2.f * cv_ + 9e-4f);  \
        const float den_ =                                              \
            (m1sq_ + m2sq_ + 1e-4f) * (vs_ + 9e-4f) + 1e-8f;            \
        local += outm * (num_ / den_);                                  \
    }

__global__ __launch_bounds__(64, 2) void ssim_vreg_kernel(
    const float* __restrict__ pred,
    const float* __restrict__ target,
    const float* __restrict__ window,
    double* __restrict__ slots)        // NBLK slots, plain write per block
{
    const int t = threadIdx.x;

    // Separable 1D window from row sums; symmetric -> 6 unique taps,
    // broadcast via shuffles.
    float rsum = 0.f;
    if (t < WSZ) {
        #pragma unroll
        for (int j = 0; j < WSZ; ++j) rsum += window[t * WSZ + j];
    }
    float wv[6];
    #pragma unroll
    for (int k = 0; k < 6; ++k) wv[k] = __shfl(rsum, k, 64);

    // Block decode: 48 img x 10 bands x 8 strips.
    const int strip = blockIdx.x & (NSTRIP - 1);
    const int rem   = blockIdx.x >> 3;
    const int band  = rem % NBAND;
    const int img   = rem / NBAND;

    // Lane t covers input column band*54 + t - 5 (clamped + masked).
    const int col  = band * OUTC + t - RAD;
    const int colc = min(max(col, 0), IMGW - 1);
    const float loadm = (col >= 0 && col < IMGW) ? 1.f : 0.f;
    // Valid output lanes: 5..58 (full h-neighborhood) and col < 512.
    const float outm =
        (t >= RAD && t < RAD + OUTC && col < IMGW) ? 1.f : 0.f;

    const int base = strip * STRIPR;   // first output row; base % 16 == 0

    const float* __restrict__ p = pred   + (size_t)img * (IMGH * IMGW);
    const float* __restrict__ q = target + (size_t)img * (IMGH * IMGW);

    // Single bpermute base: tap k of lane t pulls lane (t-5+k), i.e.
    // byte addr ((t-5)<<2) + (k<<2); k<<2 folds into the DS immediate.
    const int bpbase = (t - RAD) << 2;

    // NAMED register ring: slot i holds row r (r mod 16 == i), 4 fields.
    float g0_0=0,g0_1=0,g0_2=0,g0_3=0,g0_4=0,g0_5=0,g0_6=0,g0_7=0,
          g0_8=0,g0_9=0,g0_10=0,g0_11=0,g0_12=0,g0_13=0,g0_14=0,g0_15=0;
    float g1_0=0,g1_1=0,g1_2=0,g1_3=0,g1_4=0,g1_5=0,g1_6=0,g1_7=0,
          g1_8=0,g1_9=0,g1_10=0,g1_11=0,g1_12=0,g1_13=0,g1_14=0,g1_15=0;
    float g2_0=0,g2_1=0,g2_2=0,g2_3=0,g2_4=0,g2_5=0,g2_6=0,g2_7=0,
          g2_8=0,g2_9=0,g2_10=0,g2_11=0,g2_12=0,g2_13=0,g2_14=0,g2_15=0;
    float g3_0=0,g3_1=0,g3_2=0,g3_3=0,g3_4=0,g3_5=0,g3_6=0,g3_7=0,
          g3_8=0,g3_9=0,g3_10=0,g3_11=0,g3_12=0,g3_13=0,g3_14=0,g3_15=0;
    // Named prefetch ring, depth 4 (slot = row & 3).
    float pfp_0, pfp_1, pfp_2, pfp_3, pft_0, pft_1, pft_2, pft_3;
    float local = 0.f;

    // Initial prefetch: rows base-5..base-2 into slot row&3 (base%4==0).
    ISSUE(3, base - 5)
    ISSUE(0, base - 4)
    ISSUE(1, base - 3)
    ISSUE(2, base - 2)

    // Prologue: h-blur rows base-5..base+4 into ring slots row&15.
    HROW(11, 3, base - 5)
    HROW(12, 0, base - 4)
    HROW(13, 1, base - 3)
    HROW(14, 2, base - 2)
    HROW(15, 3, base - 1)
    HROW(0,  0, base + 0)
    HROW(1,  1, base + 1)
    HROW(2,  2, base + 2)
    HROW(3,  3, base + 3)
    HROW(4,  0, base + 4)

    // Main: 4 x 16 output rows; every ring/pf reference is a named scalar.
    #pragma unroll 1
    for (int mb = 0; mb < 4; ++mb) {
        const int rb = base + mb * 16;
        HROW(5,  1, rb + 5)   VOUT(11,12,13,14,15,0,1,2,3,4,5)
        HROW(6,  2, rb + 6)   VOUT(12,13,14,15,0,1,2,3,4,5,6)
        HROW(7,  3, rb + 7)   VOUT(13,14,15,0,1,2,3,4,5,6,7)
        HROW(8,  0, rb + 8)   VOUT(14,15,0,1,2,3,4,5,6,7,8)
        HROW(9,  1, rb + 9)   VOUT(15,0,1,2,3,4,5,6,7,8,9)
        HROW(10, 2, rb + 10)  VOUT(0,1,2,3,4,5,6,7,8,9,10)
        HROW(11, 3, rb + 11)  VOUT(1,2,3,4,5,6,7,8,9,10,11)
        HROW(12, 0, rb + 12)  VOUT(2,3,4,5,6,7,8,9,10,11,12)
        HROW(13, 1, rb + 13)  VOUT(3,4,5,6,7,8,9,10,11,12,13)
        HROW(14, 2, rb + 14)  VOUT(4,5,6,7,8,9,10,11,12,13,14)
        HROW(15, 3, rb + 15)  VOUT(5,6,7,8,9,10,11,12,13,14,15)
        HROW(0,  0, rb + 16)  VOUT(6,7,8,9,10,11,12,13,14,15,0)
        HROW(1,  1, rb + 17)  VOUT(7,8,9,10,11,12,13,14,15,0,1)
        HROW(2,  2, rb + 18)  VOUT(8,9,10,11,12,13,14,15,0,1,2)
        HROW(3,  3, rb + 19)  VOUT(9,10,11,12,13,14,15,0,1,2,3)
        HROW(4,  0, rb + 20)  VOUT(10,11,12,13,14,15,0,1,2,3,4)
    }

    // Wave shuffle reduce; lane 0 writes this block's slot (no atomic).
    #pragma unroll
    for (int off = 32; off > 0; off >>= 1)
        local += __shfl_down(local, off, 64);
    if (t == 0) slots[blockIdx.x] = (double)local;
}

__global__ __launch_bounds__(256) void ssim_finalize_kernel(
    const double* __restrict__ slots, float* __restrict__ out, double invN)
{
    __shared__ double red[4];
    const int t = threadIdx.x;
    double s = 0.0;
    for (int i = t; i < NBLK; i += 256) s += slots[i];
    #pragma unroll
    for (int off = 32; off > 0; off >>= 1)
        s += __shfl_down(s, off, 64);
    const int lane = t & 63, wid = t >> 6;
    if (lane == 0) red[wid] = s;
    __syncthreads();
    if (t == 0)
        out[0] = (float)(1.0 - (red[0] + red[1] + red[2] + red[3]) * invN);
}

extern "C" void kernel_launch(void* const* d_in, const int* in_sizes, int n_in,
                              void* d_out, int out_size, void* d_ws, size_t ws_size,
                              hipStream_t stream)
{
    const float* pred   = (const float*)d_in[0];
    const float* target = (const float*)d_in[1];
    const float* window = (const float*)d_in[2];
    float*  out   = (float*)d_out;
    double* slots = (double*)d_ws;     // NBLK*8 = 30.7 KB; every slot
                                       // written each launch (poison ok).

    ssim_vreg_kernel<<<NBLK, 64, 0, stream>>>(pred, target, window, slots);

    const double invN = 1.0 / ((double)IMGN * IMGH * IMGW);
    ssim_finalize_kernel<<<1, 256, 0, stream>>>(slots, out, invN);
}

// Round 7
// 358.188 us; speedup vs baseline: 3.4100x; 1.5405x over previous
//
#include <hip/hip_runtime.h>

// SSIM loss, round-16: zero-LDS register design, RING 16 -> 12 SLOTS.
//
// Budget law confirmed 3x: cap = 512/(2*min_waves): (64,3)->84,
// (64,1)->236(<=256), waves_per_eu(4)->64, (64,2)->128 exactly.
// Round-6 at cap 128 still spilled (WRITE_SIZE 732 MB): true working
// set is ~140-160 with the 16-slot ring, i.e. 128 < need < 236.
// Only budgets reachable are 128 and 256; 256 -> allocator balloons to
// 236 -> 2-wave band -> latency-bound 243 us. So: shrink the working
// set to genuinely fit 128. An 11-tap v-window needs 11 live rows + 1
// in-flight = 12 ring slots, not 16. Ring indexed by LOCAL row
// L = ir-(base-5) (compile-time), slot = L%12; main loop = 5x12 + 4.
// Static set: 48 ring + 8 pf + 6 w + ~12 addr = 74 -> ~54 regs slack.
//  - h-blur via ds_bpermute (lane=column), zero LDS, zero barriers;
//  - 4-deep named prefetch ring, reissue-at-consume;
//  - 48 img x 10 bands(54 cols) x 8 strips(64 rows) = 3840 1-wave blocks.
// Predicted: WRITE_SIZE 732 MB -> ~0.1 MB (spill detector), FETCH ->
// ~60 MB, VALUBusy 14 -> 55-75%, Occupancy -> 35-50%, dur 463 -> 60-110.

#define WSZ    11
#define RAD    5
#define IMGN   48
#define IMGH   512
#define IMGW   512
#define OUTC   54               // valid output cols per 64-lane band
#define NBAND  10               // ceil(512/54)
#define NSTRIP 8
#define STRIPR 64               // output rows per strip
#define NBLK   (IMGN * NBAND * NSTRIP)   // 3840

// Symmetric Gaussian taps: w[k] == w[10-k], 6 unique registers. Index
// folds to a constant after unrolling (k always compile-time constant).
#define W(k) wv[(k) < 6 ? (k) : 10 - (k)]

// Issue prefetch of input row (ir) into named pf slot PFS. Row clamped
// (always a legal address); OOB rows are zeroed at consume via fm_.
#define ISSUE(PFS, ir)                                                  \
    {                                                                   \
        const int rc_ = min(max((ir), 0), IMGH - 1);                    \
        pfp_##PFS = p[rc_ * IMGW + colc];                               \
        pft_##PFS = q[rc_ * IMGW + colc];                               \
    }

// Consume pf slot PFS (input row ir), immediately reissue row ir+4 into
// the same slot, h-blur via bpermute, deposit into named ring slot SLOT.
// Tap k reads lane (t-5+k): address = bpbase + 4k; 4k in [0,40] folds
// into the DS offset immediate. Wrap garbage reaches only masked lanes.
#define HROW(SLOT, PFS, ir)                                             \
    {                                                                   \
        const float rawp_ = pfp_##PFS, rawt_ = pft_##PFS;               \
        ISSUE(PFS, (ir) + 4)                                            \
        const float fm_ =                                               \
            ((unsigned)(ir) < (unsigned)IMGH) ? loadm : 0.f;            \
        const float pv_ = rawp_ * fm_;                                  \
        const float tv_ = rawt_ * fm_;                                  \
        const int pb_ = __float_as_int(pv_);                            \
        const int tb_ = __float_as_int(tv_);                            \
        float f0_ = W(RAD) * pv_;                                       \
        float f1_ = W(RAD) * tv_;                                       \
        float f2_ = W(RAD) * (pv_ * pv_ + tv_ * tv_);                   \
        float f3_ = W(RAD) * (pv_ * tv_);                               \
        _Pragma("unroll")                                               \
        for (int k = 0; k < WSZ; ++k) {                                 \
            if (k == RAD) continue;                                     \
            const float sp_ = __int_as_float(                           \
                __builtin_amdgcn_ds_bpermute(bpbase + (k << 2), pb_));  \
            const float st_ = __int_as_float(                           \
                __builtin_amdgcn_ds_bpermute(bpbase + (k << 2), tb_));  \
            f0_ += W(k) * sp_;                                          \
            f1_ += W(k) * st_;                                          \
            f2_ += W(k) * (sp_ * sp_ + st_ * st_);                      \
            f3_ += W(k) * (sp_ * st_);                                  \
        }                                                               \
        g0_##SLOT = f0_; g1_##SLOT = f1_;                               \
        g2_##SLOT = f2_; g3_##SLOT = f3_;                               \
    }

// Vertical 11-tap over 11 NAMED ring slots (S0..S10 = rows m-5..m+5,
// weights W(0)..W(10)) + SSIM accumulate.
#define VOUT(S0,S1,S2,S3,S4,S5,S6,S7,S8,S9,S10)                         \
    {                                                                   \
        const float a0_ =                                               \
            W(0)*g0_##S0 + W(1)*g0_##S1 + W(2)*g0_##S2 + W(3)*g0_##S3   \
          + W(4)*g0_##S4 + W(5)*g0_##S5 + W(6)*g0_##S6 + W(7)*g0_##S7   \
          + W(8)*g0_##S8 + W(9)*g0_##S9 + W(10)*g0_##S10;               \
        const float a1_ =                                               \
            W(0)*g1_##S0 + W(1)*g1_##S1 + W(2)*g1_##S2 + W(3)*g1_##S3   \
          + W(4)*g1_##S4 + W(5)*g1_##S5 + W(6)*g1_##S6 + W(7)*g1_##S7   \
          + W(8)*g1_##S8 + W(9)*g1_##S9 + W(10)*g1_##S10;               \
        const float a2_ =                                               \
            W(0)*g2_##S0 + W(1)*g2_##S1 + W(2)*g2_##S2 + W(3)*g2_##S3   \
          + W(4)*g2_##S4 + W(5)*g2_##S5 + W(6)*g2_##S6 + W(7)*g2_##S7   \
          + W(8)*g2_##S8 + W(9)*g2_##S9 + W(10)*g2_##S10;               \
        const float a3_ =                                               \
            W(0)*g3_##S0 + W(1)*g3_##S1 + W(2)*g3_##S2 + W(3)*g3_##S3   \
          + W(4)*g3_##S4 + W(5)*g3_##S5 + W(6)*g3_##S6 + W(7)*g3_##S7   \
          + W(8)*g3_##S8 + W(9)*g3_##S9 + W(10)*g3_##S10;               \
        const float m1_ = a0_, m2_ = a1_;                               \
        const float m1sq_ = m1_ * m1_, m2sq_ = m2_ * m2_;               \
        const float m12_ = m1_ * m2_;                                   \
        const float vs_ = a2_ - m1sq_ - m2sq_;                          \
        const float cv_ = a3_ - m12_;                                   \
        const float num_ = (2.f * m12_ + 1e-4f) * (2.f * cv_ + 9e-4f);  \
        const float den_ =                                              \
            (m1sq_ + m2sq_ + 1e-4f) * (vs_ + 9e-4f) + 1e-8f;            \
        local += outm * (num_ / den_);                                  \
    }

__global__ __launch_bounds__(64, 2) void ssim_vreg_kernel(
    const float* __restrict__ pred,
    const float* __restrict__ target,
    const float* __restrict__ window,
    double* __restrict__ slots)        // NBLK slots, plain write per block
{
    const int t = threadIdx.x;

    // Separable 1D window from row sums; symmetric -> 6 unique taps,
    // broadcast via shuffles.
    float rsum = 0.f;
    if (t < WSZ) {
        #pragma unroll
        for (int j = 0; j < WSZ; ++j) rsum += window[t * WSZ + j];
    }
    float wv[6];
    #pragma unroll
    for (int k = 0; k < 6; ++k) wv[k] = __shfl(rsum, k, 64);

    // Block decode: 48 img x 10 bands x 8 strips.
    const int strip = blockIdx.x & (NSTRIP - 1);
    const int rem   = blockIdx.x >> 3;
    const int band  = rem % NBAND;
    const int img   = rem / NBAND;

    // Lane t covers input column band*54 + t - 5 (clamped + masked).
    const int col  = band * OUTC + t - RAD;
    const int colc = min(max(col, 0), IMGW - 1);
    const float loadm = (col >= 0 && col < IMGW) ? 1.f : 0.f;
    // Valid output lanes: 5..58 (full h-neighborhood) and col < 512.
    const float outm =
        (t >= RAD && t < RAD + OUTC && col < IMGW) ? 1.f : 0.f;

    const int base = strip * STRIPR;   // first output row

    const float* __restrict__ p = pred   + (size_t)img * (IMGH * IMGW);
    const float* __restrict__ q = target + (size_t)img * (IMGH * IMGW);

    // Single bpermute base: tap k of lane t pulls lane (t-5+k), i.e.
    // byte addr ((t-5)<<2) + (k<<2); k<<2 folds into the DS immediate.
    const int bpbase = (t - RAD) << 2;

    // NAMED 12-slot register ring (11 live rows + 1 in-flight), 4 fields.
    // Slot = L % 12 where L = ir - (base-5) is a compile-time offset.
    float g0_0=0,g0_1=0,g0_2=0,g0_3=0,g0_4=0,g0_5=0,
          g0_6=0,g0_7=0,g0_8=0,g0_9=0,g0_10=0,g0_11=0;
    float g1_0=0,g1_1=0,g1_2=0,g1_3=0,g1_4=0,g1_5=0,
          g1_6=0,g1_7=0,g1_8=0,g1_9=0,g1_10=0,g1_11=0;
    float g2_0=0,g2_1=0,g2_2=0,g2_3=0,g2_4=0,g2_5=0,
          g2_6=0,g2_7=0,g2_8=0,g2_9=0,g2_10=0,g2_11=0;
    float g3_0=0,g3_1=0,g3_2=0,g3_3=0,g3_4=0,g3_5=0,
          g3_6=0,g3_7=0,g3_8=0,g3_9=0,g3_10=0,g3_11=0;
    // Named prefetch ring, depth 4 (slot = L & 3).
    float pfp_0, pfp_1, pfp_2, pfp_3, pft_0, pft_1, pft_2, pft_3;
    float local = 0.f;

    // Initial prefetch: L=0..3 (rows base-5..base-2) into slots 0..3.
    ISSUE(0, base - 5)
    ISSUE(1, base - 4)
    ISSUE(2, base - 3)
    ISSUE(3, base - 2)

    // Prologue: h-blur L=0..9 (rows base-5..base+4), slot L%12, pf L&3.
    HROW(0, 0, base - 5)
    HROW(1, 1, base - 4)
    HROW(2, 2, base - 3)
    HROW(3, 3, base - 2)
    HROW(4, 0, base - 1)
    HROW(5, 1, base + 0)
    HROW(6, 2, base + 1)
    HROW(7, 3, base + 2)
    HROW(8, 0, base + 3)
    HROW(9, 1, base + 4)

    // Main: 5 x 12 output rows. Output u = ub*12 + v; HROW L = u+10
    // (slot (v+10)%12, pf (v+2)&3), VOUT reads slots (v+j)%12.
    #pragma unroll 1
    for (int ub = 0; ub < 5; ++ub) {
        const int rb = base + ub * 12;
        HROW(10, 2, rb + 5)   VOUT(0,1,2,3,4,5,6,7,8,9,10)
        HROW(11, 3, rb + 6)   VOUT(1,2,3,4,5,6,7,8,9,10,11)
        HROW(0,  0, rb + 7)   VOUT(2,3,4,5,6,7,8,9,10,11,0)
        HROW(1,  1, rb + 8)   VOUT(3,4,5,6,7,8,9,10,11,0,1)
        HROW(2,  2, rb + 9)   VOUT(4,5,6,7,8,9,10,11,0,1,2)
        HROW(3,  3, rb + 10)  VOUT(5,6,7,8,9,10,11,0,1,2,3)
        HROW(4,  0, rb + 11)  VOUT(6,7,8,9,10,11,0,1,2,3,4)
        HROW(5,  1, rb + 12)  VOUT(7,8,9,10,11,0,1,2,3,4,5)
        HROW(6,  2, rb + 13)  VOUT(8,9,10,11,0,1,2,3,4,5,6)
        HROW(7,  3, rb + 14)  VOUT(9,10,11,0,1,2,3,4,5,6,7)
        HROW(8,  0, rb + 15)  VOUT(10,11,0,1,2,3,4,5,6,7,8)
        HROW(9,  1, rb + 16)  VOUT(11,0,1,2,3,4,5,6,7,8,9)
    }

    // Tail: outputs u=60..63 (v=0..3 of a 6th block).
    {
        const int rt = base + 60;
        HROW(10, 2, rt + 5)   VOUT(0,1,2,3,4,5,6,7,8,9,10)
        HROW(11, 3, rt + 6)   VOUT(1,2,3,4,5,6,7,8,9,10,11)
        HROW(0,  0, rt + 7)   VOUT(2,3,4,5,6,7,8,9,10,11,0)
        HROW(1,  1, rt + 8)   VOUT(3,4,5,6,7,8,9,10,11,0,1)
    }

    // Wave shuffle reduce; lane 0 writes this block's slot (no atomic).
    #pragma unroll
    for (int off = 32; off > 0; off >>= 1)
        local += __shfl_down(local, off, 64);
    if (t == 0) slots[blockIdx.x] = (double)local;
}

__global__ __launch_bounds__(256) void ssim_finalize_kernel(
    const double* __restrict__ slots, float* __restrict__ out, double invN)
{
    __shared__ double red[4];
    const int t = threadIdx.x;
    double s = 0.0;
    for (int i = t; i < NBLK; i += 256) s += slots[i];
    #pragma unroll
    for (int off = 32; off > 0; off >>= 1)
        s += __shfl_down(s, off, 64);
    const int lane = t & 63, wid = t >> 6;
    if (lane == 0) red[wid] = s;
    __syncthreads();
    if (t == 0)
        out[0] = (float)(1.0 - (red[0] + red[1] + red[2] + red[3]) * invN);
}

extern "C" void kernel_launch(void* const* d_in, const int* in_sizes, int n_in,
                              void* d_out, int out_size, void* d_ws, size_t ws_size,
                              hipStream_t stream)
{
    const float* pred   = (const float*)d_in[0];
    const float* target = (const float*)d_in[1];
    const float* window = (const float*)d_in[2];
    float*  out   = (float*)d_out;
    double* slots = (double*)d_ws;     // NBLK*8 = 30.7 KB; every slot
                                       // written each launch (poison ok).

    ssim_vreg_kernel<<<NBLK, 64, 0, stream>>>(pred, target, window, slots);

    const double invN = 1.0 / ((double)IMGN * IMGH * IMGW);
    ssim_finalize_kernel<<<1, 256, 0, stream>>>(slots, out, invN);
}

// Round 8
// 238.254 us; speedup vs baseline: 5.1266x; 1.5034x over previous
//
#include <hip/hip_runtime.h>

// SSIM loss, round-17: V-FIRST zero-LDS register design.
//
// Rounds 2-7 lesson: H-first ring stores 4 h-blurred fields = 48 VGPR of
// architectural state; + ~50 transient (bulked bpermutes, pipelined
// loads) -> can't fit the 128 cap (spill, 266us) and balloons to 236 at
// uncapped (2-wave band, 243us). Both lose to the 112us LDS baseline.
// Fix: blur VERTICALLY first — the ring then holds RAW p,t rows:
//  - ring 16 slots x 2 fields = 32 VGPR (was 48+8); prefetch ring MERGES
//    into the data ring (loads land in ring slots; 5-row in-flight
//    distance = ~2500 cyc latency cover);
//  - weights in SGPRs via readlane; row-OOB masking via s_cselect on the
//    weight (scalar pipe, zero VALU), col masking = 4 muls on v-sums;
//  - h-pass: 10 taps x 4 bpermutes on the v-blurred fields (40 DS/row,
//    under the VALU shadow), SSIM with v_rcp.
// Static ~42 VGPR, peak ~100 < 128 cap with real margin.
//  - 48 img x 10 bands(54 cols) x 8 strips(64 rows) = 3840 1-wave blocks,
//    zero LDS, zero barriers. __launch_bounds__(64,2) -> cap 128 (law).
// Predicted: WRITE_SIZE 299MB -> ~0.1MB, VGPR ~100-128, VALUBusy 22->
// 55-80%, Occupancy -> 30-45%, dur 266 -> 50-80 us.

#define WSZ    11
#define RAD    5
#define IMGN   48
#define IMGH   512
#define IMGW   512
#define OUTC   54               // valid output cols per 64-lane band
#define NBAND  10               // ceil(512/54)
#define NSTRIP 8
#define STRIPR 64               // output rows per strip
#define NBLK   (IMGN * NBAND * NSTRIP)   // 3840

// Load input row (ir) directly into ring slot SLOT (raw, no VALU).
// Row clamped to a legal address; OOB rows are zeroed by e-weights.
#define ISSUE(SLOT, ir)                                                 \
    {                                                                   \
        const int rc_ = min(max((ir), 0), IMGH - 1);                    \
        rp_##SLOT = p[rc_ * IMGW + colc];                               \
        rt_##SLOT = q[rc_ * IMGW + colc];                               \
    }

// Vertical tap: accumulate ring slot SL with (row-masked, SGPR) weight EW.
#define VTAP(SL, EW)                                                    \
    {                                                                   \
        const float pk_ = rp_##SL, tk_ = rt_##SL;                       \
        v0_ += (EW) * pk_;                                              \
        v1_ += (EW) * tk_;                                              \
        v2_ += (EW) * (pk_ * pk_ + tk_ * tk_);                          \
        v3_ += (EW) * (pk_ * tk_);                                      \
    }

// Horizontal tap J (!=5): pull 4 v-blurred fields from lane t-5+J.
#define HTAP(J, WW)                                                     \
    {                                                                   \
        const float s0_ = __int_as_float(__builtin_amdgcn_ds_bpermute(  \
            bpbase + ((J) << 2), __float_as_int(v0_)));                 \
        const float s1_ = __int_as_float(__builtin_amdgcn_ds_bpermute(  \
            bpbase + ((J) << 2), __float_as_int(v1_)));                 \
        const float s2_ = __int_as_float(__builtin_amdgcn_ds_bpermute(  \
            bpbase + ((J) << 2), __float_as_int(v2_)));                 \
        const float s3_ = __int_as_float(__builtin_amdgcn_ds_bpermute(  \
            bpbase + ((J) << 2), __float_as_int(v3_)));                 \
        h0_ += (WW) * s0_;                                              \
        h1_ += (WW) * s1_;                                              \
        h2_ += (WW) * s2_;                                              \
        h3_ += (WW) * s3_;                                              \
    }

// One output row MM: prefetch row MM+10 into slot PF, v-blur rows
// MM-5..MM+5 from ring slots SA..SK, mask edge cols, h-blur via
// bpermute, SSIM accumulate. All slot indices compile-time.
#define OROW(SA,SB,SC,SD,SE,SF,SG,SH,SI,SJ,SK, PF, MM)                  \
    {                                                                   \
        ISSUE(PF, (MM) + 10)                                            \
        const int rr_ = (MM) - RAD;                                     \
        const float e0_  = ((unsigned)(rr_+0)  < (unsigned)IMGH) ? wv0 : 0.f; \
        const float e1_  = ((unsigned)(rr_+1)  < (unsigned)IMGH) ? wv1 : 0.f; \
        const float e2_  = ((unsigned)(rr_+2)  < (unsigned)IMGH) ? wv2 : 0.f; \
        const float e3_  = ((unsigned)(rr_+3)  < (unsigned)IMGH) ? wv3 : 0.f; \
        const float e4_  = ((unsigned)(rr_+4)  < (unsigned)IMGH) ? wv4 : 0.f; \
        const float e5_  = ((unsigned)(rr_+5)  < (unsigned)IMGH) ? wv5 : 0.f; \
        const float e6_  = ((unsigned)(rr_+6)  < (unsigned)IMGH) ? wv4 : 0.f; \
        const float e7_  = ((unsigned)(rr_+7)  < (unsigned)IMGH) ? wv3 : 0.f; \
        const float e8_  = ((unsigned)(rr_+8)  < (unsigned)IMGH) ? wv2 : 0.f; \
        const float e9_  = ((unsigned)(rr_+9)  < (unsigned)IMGH) ? wv1 : 0.f; \
        const float e10_ = ((unsigned)(rr_+10) < (unsigned)IMGH) ? wv0 : 0.f; \
        float v0_ = 0.f, v1_ = 0.f, v2_ = 0.f, v3_ = 0.f;               \
        VTAP(SA, e0_) VTAP(SB, e1_) VTAP(SC, e2_) VTAP(SD, e3_)         \
        VTAP(SE, e4_) VTAP(SF, e5_) VTAP(SG, e6_) VTAP(SH, e7_)         \
        VTAP(SI, e8_) VTAP(SJ, e9_) VTAP(SK, e10_)                      \
        v0_ *= loadm; v1_ *= loadm; v2_ *= loadm; v3_ *= loadm;         \
        float h0_ = wv5 * v0_, h1_ = wv5 * v1_;                         \
        float h2_ = wv5 * v2_, h3_ = wv5 * v3_;                         \
        HTAP(0, wv0) HTAP(1, wv1) HTAP(2, wv2) HTAP(3, wv3)             \
        HTAP(4, wv4) HTAP(6, wv4) HTAP(7, wv3) HTAP(8, wv2)             \
        HTAP(9, wv1) HTAP(10, wv0)                                      \
        const float m1_ = h0_, m2_ = h1_;                               \
        const float m1sq_ = m1_ * m1_, m2sq_ = m2_ * m2_;               \
        const float m12_ = m1_ * m2_;                                   \
        const float vs_ = h2_ - m1sq_ - m2sq_;                          \
        const float cv_ = h3_ - m12_;                                   \
        const float num_ = (2.f * m12_ + 1e-4f) * (2.f * cv_ + 9e-4f);  \
        const float den_ =                                              \
            (m1sq_ + m2sq_ + 1e-4f) * (vs_ + 9e-4f) + 1e-8f;            \
        local += outm * num_ * __builtin_amdgcn_rcpf(den_);             \
    }

__global__ __launch_bounds__(64, 2) void ssim_vreg_kernel(
    const float* __restrict__ pred,
    const float* __restrict__ target,
    const float* __restrict__ window,
    double* __restrict__ slots)        // NBLK slots, plain write per block
{
    const int t = threadIdx.x;

    // Separable 1D window from row sums; symmetric -> 6 unique taps.
    // readlane forces the weights into SGPRs (FMA: 1 SGPR operand legal;
    // row-masking becomes s_cselect on the scalar pipe).
    float rsum = 0.f;
    if (t < WSZ) {
        #pragma unroll
        for (int j = 0; j < WSZ; ++j) rsum += window[t * WSZ + j];
    }
    const float wv0 = __int_as_float(
        __builtin_amdgcn_readlane(__float_as_int(rsum), 0));
    const float wv1 = __int_as_float(
        __builtin_amdgcn_readlane(__float_as_int(rsum), 1));
    const float wv2 = __int_as_float(
        __builtin_amdgcn_readlane(__float_as_int(rsum), 2));
    const float wv3 = __int_as_float(
        __builtin_amdgcn_readlane(__float_as_int(rsum), 3));
    const float wv4 = __int_as_float(
        __builtin_amdgcn_readlane(__float_as_int(rsum), 4));
    const float wv5 = __int_as_float(
        __builtin_amdgcn_readlane(__float_as_int(rsum), 5));

    // Block decode: 48 img x 10 bands x 8 strips.
    const int strip = blockIdx.x & (NSTRIP - 1);
    const int rem   = blockIdx.x >> 3;
    const int band  = rem % NBAND;
    const int img   = rem / NBAND;

    // Lane t covers input column band*54 + t - 5 (clamped + masked).
    const int col  = band * OUTC + t - RAD;
    const int colc = min(max(col, 0), IMGW - 1);
    const float loadm = (col >= 0 && col < IMGW) ? 1.f : 0.f;
    // Valid output lanes: 5..58 (full h-neighborhood) and col < 512.
    const float outm =
        (t >= RAD && t < RAD + OUTC && col < IMGW) ? 1.f : 0.f;

    const int base = strip * STRIPR;   // first output row

    const float* __restrict__ p = pred   + (size_t)img * (IMGH * IMGW);
    const float* __restrict__ q = target + (size_t)img * (IMGH * IMGW);

    // bpermute base: tap J of lane t pulls lane (t-5+J); J<<2 folds into
    // the DS offset immediate. Wrap garbage reaches only masked lanes.
    const int bpbase = (t - RAD) << 2;

    // RAW register ring: 16 slots x (p,t). Slot of row r = (r-base+5)&15.
    // Rows m+6..m+10 are in flight (loads not yet waited) at output m.
    float rp_0, rp_1, rp_2, rp_3, rp_4, rp_5, rp_6, rp_7,
          rp_8, rp_9, rp_10, rp_11, rp_12, rp_13, rp_14, rp_15;
    float rt_0, rt_1, rt_2, rt_3, rt_4, rt_5, rt_6, rt_7,
          rt_8, rt_9, rt_10, rt_11, rt_12, rt_13, rt_14, rt_15;
    float local = 0.f;

    // Prologue: rows base-5..base+9 into slots 0..14.
    ISSUE(0,  base - 5)
    ISSUE(1,  base - 4)
    ISSUE(2,  base - 3)
    ISSUE(3,  base - 2)
    ISSUE(4,  base - 1)
    ISSUE(5,  base + 0)
    ISSUE(6,  base + 1)
    ISSUE(7,  base + 2)
    ISSUE(8,  base + 3)
    ISSUE(9,  base + 4)
    ISSUE(10, base + 5)
    ISSUE(11, base + 6)
    ISSUE(12, base + 7)
    ISSUE(13, base + 8)
    ISSUE(14, base + 9)

    // Main: 4 x 16 output rows; all slot indices static (period 16).
    #pragma unroll 1
    for (int ub = 0; ub < 4; ++ub) {
        const int mb_ = base + ub * 16;
        OROW(0,1,2,3,4,5,6,7,8,9,10,     15, mb_ + 0)
        OROW(1,2,3,4,5,6,7,8,9,10,11,     0, mb_ + 1)
        OROW(2,3,4,5,6,7,8,9,10,11,12,    1, mb_ + 2)
        OROW(3,4,5,6,7,8,9,10,11,12,13,   2, mb_ + 3)
        OROW(4,5,6,7,8,9,10,11,12,13,14,  3, mb_ + 4)
        OROW(5,6,7,8,9,10,11,12,13,14,15, 4, mb_ + 5)
        OROW(6,7,8,9,10,11,12,13,14,15,0, 5, mb_ + 6)
        OROW(7,8,9,10,11,12,13,14,15,0,1, 6, mb_ + 7)
        OROW(8,9,10,11,12,13,14,15,0,1,2, 7, mb_ + 8)
        OROW(9,10,11,12,13,14,15,0,1,2,3, 8, mb_ + 9)
        OROW(10,11,12,13,14,15,0,1,2,3,4, 9, mb_ + 10)
        OROW(11,12,13,14,15,0,1,2,3,4,5, 10, mb_ + 11)
        OROW(12,13,14,15,0,1,2,3,4,5,6,  11, mb_ + 12)
        OROW(13,14,15,0,1,2,3,4,5,6,7,   12, mb_ + 13)
        OROW(14,15,0,1,2,3,4,5,6,7,8,    13, mb_ + 14)
        OROW(15,0,1,2,3,4,5,6,7,8,9,     14, mb_ + 15)
    }

    // Wave shuffle reduce; lane 0 writes this block's slot (no atomic).
    #pragma unroll
    for (int off = 32; off > 0; off >>= 1)
        local += __shfl_down(local, off, 64);
    if (t == 0) slots[blockIdx.x] = (double)local;
}

__global__ __launch_bounds__(256) void ssim_finalize_kernel(
    const double* __restrict__ slots, float* __restrict__ out, double invN)
{
    __shared__ double red[4];
    const int t = threadIdx.x;
    double s = 0.0;
    for (int i = t; i < NBLK; i += 256) s += slots[i];
    #pragma unroll
    for (int off = 32; off > 0; off >>= 1)
        s += __shfl_down(s, off, 64);
    const int lane = t & 63, wid = t >> 6;
    if (lane == 0) red[wid] = s;
    __syncthreads();
    if (t == 0)
        out[0] = (float)(1.0 - (red[0] + red[1] + red[2] + red[3]) * invN);
}

extern "C" void kernel_launch(void* const* d_in, const int* in_sizes, int n_in,
                              void* d_out, int out_size, void* d_ws, size_t ws_size,
                              hipStream_t stream)
{
    const float* pred   = (const float*)d_in[0];
    const float* target = (const float*)d_in[1];
    const float* window = (const float*)d_in[2];
    float*  out   = (float*)d_out;
    double* slots = (double*)d_ws;     // NBLK*8 = 30.7 KB; every slot
                                       // written each launch (poison ok).

    ssim_vreg_kernel<<<NBLK, 64, 0, stream>>>(pred, target, window, slots);

    const double invN = 1.0 / ((double)IMGN * IMGH * IMGW);
    ssim_finalize_kernel<<<1, 256, 0, stream>>>(slots, out, invN);
}

// Round 10
// 180.062 us; speedup vs baseline: 6.7833x; 1.3232x over previous
//
#include <hip/hip_runtime.h>

// SSIM loss, round-18: V-first register design, BPERMUTE -> DPP SHIFTS.
// (Round-19 resubmit: round-18 bench hit GPUAcquisitionTimeout; no data.)
//
// Round-8 post-mortem: spill dead (WRITE 120 B, VGPR 128), 155 us, but
// VALUBusy stuck at 34%. Pipe arithmetic: row period 5810 cyc; VALU
// explains ~2000; the rest is the per-CU DS pipe: 15 resident waves x
// 40 ds_bpermute/row x ~8 cyc ~= 4800 cyc/row ~= 83% DS busy. The
// kernel is DS-pipe-bound (shared per CU -> more waves can't help).
// Fix: h-blur via DPP wave shifts on the VALU pipe (34% busy) instead
// of bpermute on the DS pipe (83%): chain wave_shl1/wave_shr1
// (ctrl 0x130/0x138, 0-fill bound_ctrl) 5 deep each direction per
// field = 40 v_mov_dpp + 40 FMA per row, ZERO DS ops, zero lgkmcnt.
// 0-fill edges land only in outm-masked lanes; symmetric weights make
// the sum direction-agnostic. Everything else identical to round 8:
//  - raw 16-slot x (p,t) register ring, prefetch merged (5-row cover);
//  - weights in SGPRs (readlane), row-masks via uniform cselect;
//  - 48 img x 10 bands(54) x 8 strips(64) = 3840 1-wave blocks;
//  - __launch_bounds__(64,2) -> cap 128 (budget law, 4 waves/SIMD).
// Predicted: dur 155 -> 65-90 us, VALUBusy 34 -> 60-80%, WRITE ~120 B,
// VGPR <= 128, FETCH ~56 MB.

#define WSZ    11
#define RAD    5
#define IMGN   48
#define IMGH   512
#define IMGW   512
#define OUTC   54               // valid output cols per 64-lane band
#define NBAND  10               // ceil(512/54)
#define NSTRIP 8
#define STRIPR 64               // output rows per strip
#define NBLK   (IMGN * NBAND * NSTRIP)   // 3840

// DPP wave shifts (full-wave, VALU pipe, 0-fill at wave edge).
// FROM_L1: lane t <- lane t-1 (WF_SHL1 0x130); FROM_R1: lane t <- t+1.
#define FROM_L1(x) __int_as_float(__builtin_amdgcn_update_dpp(          \
        0, __float_as_int(x), 0x130, 0xf, 0xf, true))
#define FROM_R1(x) __int_as_float(__builtin_amdgcn_update_dpp(          \
        0, __float_as_int(x), 0x138, 0xf, 0xf, true))

// One symmetric h-tap pair at distance k: shift all 4 fields one more
// lane outward in both directions, accumulate with weight WW.
#define HSTEP(WW)                                                       \
    l0_ = FROM_L1(l0_); l1_ = FROM_L1(l1_);                             \
    l2_ = FROM_L1(l2_); l3_ = FROM_L1(l3_);                             \
    r0_ = FROM_R1(r0_); r1_ = FROM_R1(r1_);                             \
    r2_ = FROM_R1(r2_); r3_ = FROM_R1(r3_);                             \
    h0_ += (WW) * (l0_ + r0_); h1_ += (WW) * (l1_ + r1_);               \
    h2_ += (WW) * (l2_ + r2_); h3_ += (WW) * (l3_ + r3_);

// Load input row (ir) directly into ring slot SLOT (raw, no VALU).
// Row clamped to a legal address; OOB rows are zeroed by e-weights.
#define ISSUE(SLOT, ir)                                                 \
    {                                                                   \
        const int rc_ = min(max((ir), 0), IMGH - 1);                    \
        rp_##SLOT = p[rc_ * IMGW + colc];                               \
        rt_##SLOT = q[rc_ * IMGW + colc];                               \
    }

// Vertical tap: accumulate ring slot SL with (row-masked, SGPR) weight EW.
#define VTAP(SL, EW)                                                    \
    {                                                                   \
        const float pk_ = rp_##SL, tk_ = rt_##SL;                       \
        v0_ += (EW) * pk_;                                              \
        v1_ += (EW) * tk_;                                              \
        v2_ += (EW) * (pk_ * pk_ + tk_ * tk_);                          \
        v3_ += (EW) * (pk_ * tk_);                                      \
    }

// One output row MM: prefetch row MM+10 into slot PF, v-blur rows
// MM-5..MM+5 from ring slots SA..SK, mask edge cols, h-blur via DPP
// shift chains, SSIM accumulate. All slot indices compile-time.
#define OROW(SA,SB,SC,SD,SE,SF,SG,SH,SI,SJ,SK, PF, MM)                  \
    {                                                                   \
        ISSUE(PF, (MM) + 10)                                            \
        const int rr_ = (MM) - RAD;                                     \
        const float e0_  = ((unsigned)(rr_+0)  < (unsigned)IMGH) ? wv0 : 0.f; \
        const float e1_  = ((unsigned)(rr_+1)  < (unsigned)IMGH) ? wv1 : 0.f; \
        const float e2_  = ((unsigned)(rr_+2)  < (unsigned)IMGH) ? wv2 : 0.f; \
        const float e3_  = ((unsigned)(rr_+3)  < (unsigned)IMGH) ? wv3 : 0.f; \
        const float e4_  = ((unsigned)(rr_+4)  < (unsigned)IMGH) ? wv4 : 0.f; \
        const float e5_  = ((unsigned)(rr_+5)  < (unsigned)IMGH) ? wv5 : 0.f; \
        const float e6_  = ((unsigned)(rr_+6)  < (unsigned)IMGH) ? wv4 : 0.f; \
        const float e7_  = ((unsigned)(rr_+7)  < (unsigned)IMGH) ? wv3 : 0.f; \
        const float e8_  = ((unsigned)(rr_+8)  < (unsigned)IMGH) ? wv2 : 0.f; \
        const float e9_  = ((unsigned)(rr_+9)  < (unsigned)IMGH) ? wv1 : 0.f; \
        const float e10_ = ((unsigned)(rr_+10) < (unsigned)IMGH) ? wv0 : 0.f; \
        float v0_ = 0.f, v1_ = 0.f, v2_ = 0.f, v3_ = 0.f;               \
        VTAP(SA, e0_) VTAP(SB, e1_) VTAP(SC, e2_) VTAP(SD, e3_)         \
        VTAP(SE, e4_) VTAP(SF, e5_) VTAP(SG, e6_) VTAP(SH, e7_)         \
        VTAP(SI, e8_) VTAP(SJ, e9_) VTAP(SK, e10_)                      \
        v0_ *= loadm; v1_ *= loadm; v2_ *= loadm; v3_ *= loadm;         \
        float h0_ = wv5 * v0_, h1_ = wv5 * v1_;                         \
        float h2_ = wv5 * v2_, h3_ = wv5 * v3_;                         \
        float l0_ = v0_, l1_ = v1_, l2_ = v2_, l3_ = v3_;               \
        float r0_ = v0_, r1_ = v1_, r2_ = v2_, r3_ = v3_;               \
        HSTEP(wv4) HSTEP(wv3) HSTEP(wv2) HSTEP(wv1) HSTEP(wv0)          \
        const float m1_ = h0_, m2_ = h1_;                               \
        const float m1sq_ = m1_ * m1_, m2sq_ = m2_ * m2_;               \
        const float m12_ = m1_ * m2_;                                   \
        const float vs_ = h2_ - m1sq_ - m2sq_;                          \
        const float cv_ = h3_ - m12_;                                   \
        const float num_ = (2.f * m12_ + 1e-4f) * (2.f * cv_ + 9e-4f);  \
        const float den_ =                                              \
            (m1sq_ + m2sq_ + 1e-4f) * (vs_ + 9e-4f) + 1e-8f;            \
        local += outm * num_ * __builtin_amdgcn_rcpf(den_);             \
    }

__global__ __launch_bounds__(64, 2) void ssim_vreg_kernel(
    const float* __restrict__ pred,
    const float* __restrict__ target,
    const float* __restrict__ window,
    double* __restrict__ slots)        // NBLK slots, plain write per block
{
    const int t = threadIdx.x;

    // Separable 1D window from row sums; symmetric -> 6 unique taps.
    // readlane forces the weights into SGPRs.
    float rsum = 0.f;
    if (t < WSZ) {
        #pragma unroll
        for (int j = 0; j < WSZ; ++j) rsum += window[t * WSZ + j];
    }
    const float wv0 = __int_as_float(
        __builtin_amdgcn_readlane(__float_as_int(rsum), 0));
    const float wv1 = __int_as_float(
        __builtin_amdgcn_readlane(__float_as_int(rsum), 1));
    const float wv2 = __int_as_float(
        __builtin_amdgcn_readlane(__float_as_int(rsum), 2));
    const float wv3 = __int_as_float(
        __builtin_amdgcn_readlane(__float_as_int(rsum), 3));
    const float wv4 = __int_as_float(
        __builtin_amdgcn_readlane(__float_as_int(rsum), 4));
    const float wv5 = __int_as_float(
        __builtin_amdgcn_readlane(__float_as_int(rsum), 5));

    // Block decode: 48 img x 10 bands x 8 strips.
    const int strip = blockIdx.x & (NSTRIP - 1);
    const int rem   = blockIdx.x >> 3;
    const int band  = rem % NBAND;
    const int img   = rem / NBAND;

    // Lane t covers input column band*54 + t - 5 (clamped + masked).
    const int col  = band * OUTC + t - RAD;
    const int colc = min(max(col, 0), IMGW - 1);
    const float loadm = (col >= 0 && col < IMGW) ? 1.f : 0.f;
    // Valid output lanes: 5..58 (full h-neighborhood) and col < 512.
    const float outm =
        (t >= RAD && t < RAD + OUTC && col < IMGW) ? 1.f : 0.f;

    const int base = strip * STRIPR;   // first output row

    const float* __restrict__ p = pred   + (size_t)img * (IMGH * IMGW);
    const float* __restrict__ q = target + (size_t)img * (IMGH * IMGW);

    // RAW register ring: 16 slots x (p,t). Slot of row r = (r-base+5)&15.
    // Rows m+6..m+10 are in flight (loads not yet waited) at output m.
    float rp_0, rp_1, rp_2, rp_3, rp_4, rp_5, rp_6, rp_7,
          rp_8, rp_9, rp_10, rp_11, rp_12, rp_13, rp_14, rp_15;
    float rt_0, rt_1, rt_2, rt_3, rt_4, rt_5, rt_6, rt_7,
          rt_8, rt_9, rt_10, rt_11, rt_12, rt_13, rt_14, rt_15;
    float local = 0.f;

    // Prologue: rows base-5..base+9 into slots 0..14.
    ISSUE(0,  base - 5)
    ISSUE(1,  base - 4)
    ISSUE(2,  base - 3)
    ISSUE(3,  base - 2)
    ISSUE(4,  base - 1)
    ISSUE(5,  base + 0)
    ISSUE(6,  base + 1)
    ISSUE(7,  base + 2)
    ISSUE(8,  base + 3)
    ISSUE(9,  base + 4)
    ISSUE(10, base + 5)
    ISSUE(11, base + 6)
    ISSUE(12, base + 7)
    ISSUE(13, base + 8)
    ISSUE(14, base + 9)

    // Main: 4 x 16 output rows; all slot indices static (period 16).
    #pragma unroll 1
    for (int ub = 0; ub < 4; ++ub) {
        const int mb_ = base + ub * 16;
        OROW(0,1,2,3,4,5,6,7,8,9,10,     15, mb_ + 0)
        OROW(1,2,3,4,5,6,7,8,9,10,11,     0, mb_ + 1)
        OROW(2,3,4,5,6,7,8,9,10,11,12,    1, mb_ + 2)
        OROW(3,4,5,6,7,8,9,10,11,12,13,   2, mb_ + 3)
        OROW(4,5,6,7,8,9,10,11,12,13,14,  3, mb_ + 4)
        OROW(5,6,7,8,9,10,11,12,13,14,15, 4, mb_ + 5)
        OROW(6,7,8,9,10,11,12,13,14,15,0, 5, mb_ + 6)
        OROW(7,8,9,10,11,12,13,14,15,0,1, 6, mb_ + 7)
        OROW(8,9,10,11,12,13,14,15,0,1,2, 7, mb_ + 8)
        OROW(9,10,11,12,13,14,15,0,1,2,3, 8, mb_ + 9)
        OROW(10,11,12,13,14,15,0,1,2,3,4, 9, mb_ + 10)
        OROW(11,12,13,14,15,0,1,2,3,4,5, 10, mb_ + 11)
        OROW(12,13,14,15,0,1,2,3,4,5,6,  11, mb_ + 12)
        OROW(13,14,15,0,1,2,3,4,5,6,7,   12, mb_ + 13)
        OROW(14,15,0,1,2,3,4,5,6,7,8,    13, mb_ + 14)
        OROW(15,0,1,2,3,4,5,6,7,8,9,     14, mb_ + 15)
    }

    // Wave shuffle reduce; lane 0 writes this block's slot (no atomic).
    #pragma unroll
    for (int off = 32; off > 0; off >>= 1)
        local += __shfl_down(local, off, 64);
    if (t == 0) slots[blockIdx.x] = (double)local;
}

__global__ __launch_bounds__(256) void ssim_finalize_kernel(
    const double* __restrict__ slots, float* __restrict__ out, double invN)
{
    __shared__ double red[4];
    const int t = threadIdx.x;
    double s = 0.0;
    for (int i = t; i < NBLK; i += 256) s += slots[i];
    #pragma unroll
    for (int off = 32; off > 0; off >>= 1)
        s += __shfl_down(s, off, 64);
    const int lane = t & 63, wid = t >> 6;
    if (lane == 0) red[wid] = s;
    __syncthreads();
    if (t == 0)
        out[0] = (float)(1.0 - (red[0] + red[1] + red[2] + red[3]) * invN);
}

extern "C" void kernel_launch(void* const* d_in, const int* in_sizes, int n_in,
                              void* d_out, int out_size, void* d_ws, size_t ws_size,
                              hipStream_t stream)
{
    const float* pred   = (const float*)d_in[0];
    const float* target = (const float*)d_in[1];
    const float* window = (const float*)d_in[2];
    float*  out   = (float*)d_out;
    double* slots = (double*)d_ws;     // NBLK*8 = 30.7 KB; every slot
                                       // written each launch (poison ok).

    ssim_vreg_kernel<<<NBLK, 64, 0, stream>>>(pred, target, window, slots);

    const double invN = 1.0 / ((double)IMGN * IMGH * IMGW);
    ssim_finalize_kernel<<<1, 256, 0, stream>>>(slots, out, invN);
}